// Round 19
// baseline (649.201 us; speedup 1.0000x reference)
//
#include <hip/hip_runtime.h>
#include <stdint.h>

typedef __attribute__((ext_vector_type(8))) short short8;
typedef __attribute__((ext_vector_type(4))) float f32x4;
typedef unsigned short u16;
typedef unsigned long long u64;

// ---- helpers ----
__device__ __forceinline__ u16 f2bf(float f) {
  uint32_t u = __builtin_bit_cast(uint32_t, f);
  u = (u + 0x7FFFu + ((u >> 16) & 1u)) >> 16;
  return (u16)u;
}
__device__ __forceinline__ float bf2f(u16 h) {
  uint32_t u = ((uint32_t)h) << 16;
  return __builtin_bit_cast(float, u);
}
__device__ __forceinline__ void lds16(const u16* g, u16* l) {
  __builtin_amdgcn_global_load_lds(
      (const __attribute__((address_space(1))) void*)g,
      (__attribute__((address_space(3))) void*)l, 16, 0, 0);
}
// LDS XOR swizzles on u16 indices (16B granule): involutions.
__device__ __forceinline__ int sw256(int i) { return i ^ (((i >> 7) & 7) << 3); }
__device__ __forceinline__ int sw128(int i) { return i ^ (((i >> 6) & 7) << 3); }
// 32-u16-wide rows: flip slot bits[4:3] by (row>>1)&3
__device__ __forceinline__ int swzA32(int i) { return i ^ (((i >> 6) & 3) << 3); }

#define SB0() __builtin_amdgcn_sched_barrier(0)
#define BAR() __builtin_amdgcn_s_barrier()
#define LGKM0() do { asm volatile("s_waitcnt lgkmcnt(0)" ::: "memory"); SB0(); } while (0)
#define VM(n) asm volatile("s_waitcnt vmcnt(" #n ")" ::: "memory")
#define VMNOP do {} while (0)

// ---- fused vectorized split: f32 -> bf16 hi (+ optional lo), all 5 inputs ----
__global__ __launch_bounds__(256) void split_all(
    const float* __restrict__ x,  const float* __restrict__ Wq,
    const float* __restrict__ Wk, const float* __restrict__ Wv,
    const float* __restrict__ Wo,
    u16* __restrict__ xh, u16* __restrict__ xl,
    u16* __restrict__ qh, u16* __restrict__ kh, u16* __restrict__ kl,
    u16* __restrict__ vh, u16* __restrict__ vl, u16* __restrict__ oh)
{
  const int bid = blockIdx.x, t = threadIdx.x;
  if (bid < 2048) {
    for (int i = bid * 256 + t; i < 2097152; i += 2048 * 256) {
      const float4* s = (const float4*)x + 2 * (size_t)i;
      float4 a = s[0], b = s[1];
      float v[8] = {a.x, a.y, a.z, a.w, b.x, b.y, b.z, b.w};
      short8 hi, lo;
#pragma unroll
      for (int j = 0; j < 8; j++) {
        u16 h = f2bf(v[j]);
        hi[j] = (short)h;
        lo[j] = (short)f2bf(v[j] - bf2f(h));
      }
      ((short8*)xh)[i] = hi;
      ((short8*)xl)[i] = lo;
    }
  } else {
    const int seg = (bid - 2048) >> 9;      // 0..3 : Wq, Wk, Wv, Wo
    const int sb  = (bid - 2048) & 511;
    const float* W = seg == 0 ? Wq : seg == 1 ? Wk : seg == 2 ? Wv : Wo;
    u16* H = seg == 0 ? qh : seg == 1 ? kh : seg == 2 ? vh : oh;
    u16* L = seg == 1 ? kl : seg == 2 ? vl : nullptr;
    for (int i = sb * 256 + t; i < 524288; i += 512 * 256) {
      const float4* s = (const float4*)W + 2 * (size_t)i;
      float4 a = s[0], b = s[1];
      float v[8] = {a.x, a.y, a.z, a.w, b.x, b.y, b.z, b.w};
      short8 hi, lo;
#pragma unroll
      for (int j = 0; j < 8; j++) {
        u16 h = f2bf(v[j]);
        hi[j] = (short)h;
        lo[j] = (short)f2bf(v[j] - bf2f(h));
      }
      ((short8*)H)[i] = hi;
      if (L) ((short8*)L)[i] = lo;
    }
  }
}

// ==== 256x256 GEMM, BK=32, counted-vmcnt pipeline ====
// 8 waves (2M x 4N), per-wave 128x64 out.
// SPLIT=3 (KV): 3 pass-phases/tile (hi*hi, hi*lo, lo*hi), 6 barriers/tile,
//   counted vmcnt(6)/(6)/(4) keeps stages in flight across barriers.
// SPLIT=1 (Q/O): SINGLE-phase tiles: {12 ds_reads | 4 stage rounds | 32 MFMA
//   | VM(0) | ONE barrier} -- removes the old 8-barrier/tile convoy overhead.
// NTN = number of 256-col tiles. XCD-bijective swizzle.
// EPI 0: bf16 (b,h,t,d), *qscale | EPI 1: ballot-pack signs into kpk/vpk |
// EPI 2: f32 MxN
template<int SPLIT, int EPI, int NTN>
__global__ __launch_bounds__(512, 2) void gemm8p(
    const u16* __restrict__ Ahi, const u16* __restrict__ Alo,
    const u16* __restrict__ Bhi, const u16* __restrict__ Blo,
    u16* __restrict__ outb, float* __restrict__ outf,
    u64* __restrict__ kpk_p, u64* __restrict__ vpk_p,
    int Mdim, int Ndim, int Kdim)
{
  constexpr int BK   = 32;
  constexpr int TILE = 256 * BK;                 // 8192 u16 = 16KB
  constexpr int NMAT = (SPLIT > 1) ? 4 : 2;
  constexpr int AOFF_H = 0;
  constexpr int AOFF_L = (SPLIT > 1) ? TILE : 0;
  constexpr int BOFF_H = (SPLIT > 1) ? 2*TILE : TILE;
  constexpr int BOFF_L = (SPLIT > 1) ? 3*TILE : 0;
  __shared__ __align__(16) u16 smem[2 * NMAT * TILE];   // 128KB / 64KB

  const int t = threadIdx.x, l = t & 63;
  const int w = t >> 6;
  const int wm = w >> 2, wn = w & 3;
  const int fr = l & 15, fs = l >> 4;
  // XCD-bijective block swizzle (grid = 32*NTN, % 8 == 0)
  const int sb = (blockIdx.x & 7) * (4 * NTN) + (blockIdx.x >> 3);
  const int m0 = (sb / NTN) * 256, n0 = (sb % NTN) * 256;
  const int NT = Kdim / BK;

  // stage one 8KB round (512 lanes x 16B) of matrix `src` for K-tile kt.
  auto ST = [&](const u16* src, int g0, int moff, int kt, int r) {
    if (kt >= NT) return;
    const int bufb = (kt & 1) * NMAT * TILE;
    int d = r * 4096 + t * 8;
    int row = d >> 5, scol = ((d >> 3) & 3) ^ ((row >> 1) & 3);
    lds16(src + (size_t)(g0 + row) * Kdim + kt * BK + scol * 8,
          smem + bufb + moff + d);
  };

  f32x4 acc[8][4] = {};

  auto RD8 = [&](short8* dst, int bufb, int off) {
#pragma unroll
    for (int fm = 0; fm < 8; fm++) {
      int ia = (wm*128 + fm*16 + fr)*BK + fs*8;
      dst[fm] = *(const short8*)(smem + bufb + off + swzA32(ia));
    }
  };
  auto RD4 = [&](short8* dst, int bufb, int off) {
#pragma unroll
    for (int fn = 0; fn < 4; fn++) {
      int ib = (wn*64 + fn*16 + fr)*BK + fs*8;
      dst[fn] = *(const short8*)(smem + bufb + off + swzA32(ib));
    }
  };

#define PASS32(RA, RB) do {                                                    \
  __builtin_amdgcn_s_setprio(1);                                               \
  _Pragma("unroll") for (int fm_ = 0; fm_ < 8; fm_++)                          \
    _Pragma("unroll") for (int fn_ = 0; fn_ < 4; fn_++)                        \
      acc[fm_][fn_] = __builtin_amdgcn_mfma_f32_16x16x32_bf16(                 \
          (RA)[fm_], (RB)[fn_], acc[fm_][fn_], 0, 0, 0);                       \
  __builtin_amdgcn_s_setprio(0);                                               \
  SB0();                                                                       \
} while (0)

// SPLIT=3 tile: 3 phases, stage T+1 rounds Ah,Ah,Bh,Bh | Bl,Bl | Al,Al
#define T3BODY(T, W0, W1, W2) {                                                \
  const int bufb = ((T) & 1) * NMAT * TILE;                                    \
  short8 xah[8], xbh[4], xbl[4], xal[8];                                       \
  RD8(xah, bufb, AOFF_H); RD4(xbh, bufb, BOFF_H);                              \
  ST(Ahi, m0, AOFF_H, (T)+1, 0); ST(Ahi, m0, AOFF_H, (T)+1, 1);                \
  ST(Bhi, n0, BOFF_H, (T)+1, 0); ST(Bhi, n0, BOFF_H, (T)+1, 1);                \
  W0; BAR(); LGKM0(); PASS32(xah, xbh); BAR();                                 \
  RD4(xbl, bufb, BOFF_L);                                                      \
  ST(Blo, n0, BOFF_L, (T)+1, 0); ST(Blo, n0, BOFF_L, (T)+1, 1);                \
  W1; BAR(); LGKM0(); PASS32(xah, xbl); BAR();                                 \
  RD8(xal, bufb, AOFF_L);                                                      \
  ST(Alo, m0, AOFF_L, (T)+1, 0); ST(Alo, m0, AOFF_L, (T)+1, 1);                \
  W2; BAR(); LGKM0(); PASS32(xal, xbh); BAR();                                 \
}

  if constexpr (SPLIT > 1) {
    // prologue: T0 fully staged; Ah,Bh landed, Bl,Al (4) left in flight
    ST(Ahi, m0, AOFF_H, 0, 0); ST(Ahi, m0, AOFF_H, 0, 1);
    ST(Bhi, n0, BOFF_H, 0, 0); ST(Bhi, n0, BOFF_H, 0, 1);
    ST(Blo, n0, BOFF_L, 0, 0); ST(Blo, n0, BOFF_L, 0, 1);
    ST(Alo, m0, AOFF_L, 0, 0); ST(Alo, m0, AOFF_L, 0, 1);
    VM(4); BAR();
    for (int T = 0; T < NT - 1; T++) T3BODY(T, VM(6), VM(6), VM(4))
    T3BODY(NT - 1, VM(2), VM(0), VMNOP)
  } else {
    // single-phase tiles: one barrier per tile
    ST(Ahi, m0, AOFF_H, 0, 0); ST(Ahi, m0, AOFF_H, 0, 1);
    ST(Bhi, n0, BOFF_H, 0, 0); ST(Bhi, n0, BOFF_H, 0, 1);
    VM(0); BAR();
    for (int T = 0; T < NT; T++) {
      const int cb = (T & 1) * NMAT * TILE;
      short8 a[8], bq[4];
      RD8(a, cb, AOFF_H); RD4(bq, cb, BOFF_H);
      SB0();
      ST(Ahi, m0, AOFF_H, T+1, 0); ST(Ahi, m0, AOFF_H, T+1, 1);
      ST(Bhi, n0, BOFF_H, T+1, 0); ST(Bhi, n0, BOFF_H, T+1, 1);
      SB0();
      LGKM0();
      PASS32(a, bq);
      VM(0); BAR();          // own stages landed; all waves' reads done
    }
  }
#undef T3BODY
#undef PASS32

  if constexpr (EPI == 1) {
    // ballot-pack signs into chunk words. Per (q, fn): 16 ballots; bit
    // (fs*16+fr) of bal[j][r] = sign(row j*16+fs*4+r, col fr). Lane c<16
    // assembles word for col c: bit rc = j*16+fs*4+r.
#pragma unroll
    for (int q = 0; q < 2; q++) {
#pragma unroll
      for (int fn = 0; fn < 4; fn++) {
        u64 bal[4][4];
#pragma unroll
        for (int j = 0; j < 4; j++)
#pragma unroll
          for (int r = 0; r < 4; r++)
            bal[j][r] = __ballot(acc[4*q + j][fn][r] < 0.f);
        if (l < 16) {
          u64 wq = 0;
#pragma unroll
          for (int j = 0; j < 4; j++)
#pragma unroll
            for (int r = 0; r < 4; r++) {
              u64 x = (bal[j][r] >> l) & 0x0001000100010001ULL;
              u64 y = (x & 1) | ((x >> 12) & 0x10) |
                      ((x >> 24) & 0x100) | ((x >> 36) & 0x1000);
              wq |= y << (j*16 + r);
            }
          int gmc = m0 + wm*128 + q*64;
          int gn  = n0 + wn*64 + fn*16 + l;
          int b = gmc >> 12, n = (gmc & 4095) >> 6;
          int kv = gn >> 11, h = (gn >> 7) & 15, dd = gn & 127;
          u64* dst = kv ? vpk_p : kpk_p;
          dst[((size_t)((b*16 + h)*64 + n))*128 + dd] = wq;
        }
      }
    }
  } else {
    const float qscale = 0.08838834764831843f; // 1/sqrt(128)
#pragma unroll
    for (int fm = 0; fm < 8; fm++)
#pragma unroll
      for (int fn = 0; fn < 4; fn++)
#pragma unroll
        for (int r = 0; r < 4; r++) {
          int gm = m0 + wm*128 + fm*16 + fs*4 + r;
          int gn = n0 + wn*64 + fn*16 + fr;
          float val = acc[fm][fn][r];
          if constexpr (EPI == 2) {
            outf[(size_t)gm * Ndim + gn] = val;
          } else {
            int b = gm >> 12, tt = gm & 4095, h = gn >> 7, dd = gn & 127;
            size_t idx = (((size_t)(b*16 + h))*4096 + tt)*128 + dd;
            outb[idx] = f2bf(val * qscale);
          }
        }
  }
}

// ---- parallel exact prefix-state: stride-8 int16 checkpoints + final state
//      (writes fstate [bh][d][e] directly via LDS e-pair exchange) ----
__global__ __launch_bounds__(256) void scan_kernel(
    const u64* __restrict__ kp, const u64* __restrict__ vp,
    short* __restrict__ pfx8, float* __restrict__ fstate)
{
  __shared__ float xch[256];
  const int t = threadIdx.x;
  const int bh = blockIdx.x >> 6, ep = blockIdx.x & 63;
  const int e = ep * 2 + (t >> 7), d = t & 127;
  const size_t base = (size_t)bh * 64 * 128;
  int s = 0;
  for (int n = 0; n < 64; n++) {
    if ((n & 7) == 0)
      pfx8[((size_t)(bh*8 + (n>>3))*128 + e)*128 + d] = (short)s;
    u64 kw = kp[base + (size_t)n*128 + d];
    u64 vw = vp[base + (size_t)n*128 + e];
    s += 64 - 2*__popcll(kw ^ vw);
  }
  xch[t] = (float)s;
  __syncthreads();
  if (t < 128) {
    float2 p;
    p.x = xch[t];          // (e = 2*ep,   d = t)
    p.y = xch[t + 128];    // (e = 2*ep+1, d = t)
    *(float2*)&fstate[((size_t)bh*128 + t)*128 + ep*2] = p;
  }
}

// ---- fused intra + cross per (b,h,chunk): fully parallel over 2048 blocks ----
// Q held in REGISTERS (4 short8/lane, wave-local rows, reused 3x). LDS 32KB.
__global__ __launch_bounds__(256) void fused_attn(
    const u16* __restrict__ q,
    const u64* __restrict__ kp, const u64* __restrict__ vp,
    const short* __restrict__ pfx8, u16* __restrict__ att)
{
  __shared__ __align__(16) u16 smem[16384];  // 32KB
  u16* sP1 = smem;          // K [64][128] sw256 -> PThi [64][128] sw256
  u16* sP2 = smem + 8192;   // V^T [128][64] sw128 -> PTlo [64][128] sw256
  u16* sS  = sP1 + 4096;    // [64][64] sw128, OVERLAYS sP1 rows 32-63

  const int t = threadIdx.x, l = t & 63, w = t >> 6;
  const int blk = blockIdx.x, bh = blk >> 6, n = blk & 63;
  const int b = bh >> 4, hh = bh & 15;
  const int fr = l & 15, fs = l >> 4;
  const size_t qbase = (((size_t)bh * 4096) + n * 64) * 128;
  const size_t pbase = (size_t)bh * 64 * 128;

  // Q fragments direct global->reg (issued first; latency hides under unpack)
  short8 qv[4];
#pragma unroll
  for (int kk = 0; kk < 4; kk++)
    qv[kk] = *(const short8*)(q + qbase + (size_t)(w*16 + fr)*128 + kk*32 + fs*8);

  // unpack K (row-major [c][d], sw256) and V^T ([d][c], sw128) from bit words
  {
    const u64* krow = kp + pbase + (size_t)n*128;
    int d = (t & 63) * 2, c0 = (t >> 6) * 16;
    u64 w0 = krow[d], w1 = krow[d+1];
#pragma unroll
    for (int i = 0; i < 16; i++) {
      int c = c0 + i;
      uint32_t b0 = ((w0 >> c) & 1ull) ? 0xBF80u : 0x3F80u;
      uint32_t b1 = ((w1 >> c) & 1ull) ? 0xBF80u : 0x3F80u;
      *(uint32_t*)(sP1 + sw256(c*128 + d)) = b0 | (b1 << 16);
    }
  }
  {
    int d = t >> 1, ch = (t & 1) * 32;
    u64 wv = vp[pbase + (size_t)n*128 + d];
#pragma unroll
    for (int c = 0; c < 32; c += 2) {
      uint32_t b0 = ((wv >> (ch + c)) & 1ull)     ? 0xBF80u : 0x3F80u;
      uint32_t b1 = ((wv >> (ch + c + 1)) & 1ull) ? 0xBF80u : 0x3F80u;
      int li = d*64 + ch + c;
      *(uint32_t*)(sP2 + sw128(li)) = b0 | (b1 << 16);
    }
  }
  __syncthreads();

  // phase B: scores = Q K^T, causal mask
  f32x4 accS[4] = {};
#pragma unroll
  for (int kk = 0; kk < 4; kk++) {
#pragma unroll
    for (int fn = 0; fn < 4; fn++) {
      int lb = (fn*16 + fr)*128 + kk*32 + fs*8;
      short8 bb = *(const short8*)(sP1 + sw256(lb));
      accS[fn] = __builtin_amdgcn_mfma_f32_16x16x32_bf16(qv[kk], bb, accS[fn], 0, 0, 0);
    }
  }
  __syncthreads();   // all waves done reading sP1(K) before sS overlay write
#pragma unroll
  for (int fn = 0; fn < 4; fn++)
#pragma unroll
    for (int r = 0; r < 4; r++) {
      int i = w*16 + fs*4 + r, j = fn*16 + fr;
      float v = (j <= i) ? accS[fn][r] : 0.f;
      sS[sw128(i*64 + j)] = f2bf(v);
    }
  __syncthreads();

  // phase C: intra = sS @ V
  f32x4 accI[8] = {};
#pragma unroll
  for (int kk = 0; kk < 2; kk++) {
    int la = (w*16 + fr)*64 + kk*32 + fs*8;
    short8 a = *(const short8*)(sS + sw128(la));
#pragma unroll
    for (int fn = 0; fn < 8; fn++) {
      int lb = (fn*16 + fr)*64 + kk*32 + fs*8;
      short8 bb = *(const short8*)(sP2 + sw128(lb));
      accI[fn] = __builtin_amdgcn_mfma_f32_16x16x32_bf16(a, bb, accI[fn], 0, 0, 0);
    }
  }
  __syncthreads();

  // cross term, two e-halves; prefix rebuilt exactly per half
  const int m0 = n & ~7, cnt = n & 7;
  for (int hf = 0; hf < 2; hf++) {
#pragma unroll
    for (int p = 0; p < 4; p++) {
      int erow = p*16 + (t>>4);
      int e = hf*64 + erow;
      const short* ps = pfx8 + ((size_t)(bh*8 + (n>>3))*128 + e)*128 + (t&15)*8;
      short8 pv = *(const short8*)ps;
      int accj[8];
#pragma unroll
      for (int j = 0; j < 8; j++) accj[j] = pv[j];
      for (int m = 0; m < cnt; m++) {
        u64 vw = vp[pbase + (size_t)(m0+m)*128 + e];
#pragma unroll
        for (int j = 0; j < 8; j++) {
          u64 kw = kp[pbase + (size_t)(m0+m)*128 + (t&15)*8 + j];
          accj[j] += 64 - 2*__popcll(kw ^ vw);
        }
      }
      short8 hi, lo;
#pragma unroll
      for (int j = 0; j < 8; j++) {
        hi[j] = (short)f2bf((float)(accj[j] >> 5));
        lo[j] = (short)f2bf((float)(accj[j] & 31));
      }
      int pi = sw256(erow*128 + (t&15)*8);
      *(short8*)(sP1 + pi) = hi;
      *(short8*)(sP2 + pi) = lo;
    }
    __syncthreads();

    f32x4 acch[4] = {}, accl[4] = {};
#pragma unroll
    for (int kk = 0; kk < 4; kk++) {
#pragma unroll
      for (int fn = 0; fn < 4; fn++) {
        int pb = sw256((fn*16 + fr)*128 + kk*32 + fs*8);
        acch[fn] = __builtin_amdgcn_mfma_f32_16x16x32_bf16(qv[kk], *(const short8*)(sP1 + pb), acch[fn], 0, 0, 0);
        accl[fn] = __builtin_amdgcn_mfma_f32_16x16x32_bf16(qv[kk], *(const short8*)(sP2 + pb), accl[fn], 0, 0, 0);
      }
    }
#pragma unroll
    for (int fn = 0; fn < 4; fn++)
#pragma unroll
      for (int r = 0; r < 4; r++) {
        int c = w*16 + fs*4 + r;
        int dcol = hf*64 + fn*16 + fr;
        float val = accI[hf*4+fn][r] + 32.f*acch[fn][r] + accl[fn][r];
        size_t idx = ((size_t)(b*4096 + n*64 + c))*2048 + hh*128 + dcol;
        att[idx] = f2bf(val);
      }
    __syncthreads();  // before next half overwrites sP1/sP2
  }
}

extern "C" void kernel_launch(void* const* d_in, const int* in_sizes, int n_in,
                              void* d_out, int out_size, void* d_ws, size_t ws_size,
                              hipStream_t stream) {
  (void)in_sizes; (void)n_in; (void)out_size; (void)ws_size;
  const float* x  = (const float*)d_in[0];
  const float* Wq = (const float*)d_in[1];
  const float* Wk = (const float*)d_in[2];
  const float* Wv = (const float*)d_in[3];
  const float* Wo = (const float*)d_in[4];
  float* out = (float*)d_out;
  float* fstate = out + (size_t)16777216; // B*T*D

  char* ws = (char*)d_ws;
  u16* x_hi = (u16*)(ws + 0);           // later aliased as att
  u16* x_lo = (u16*)(ws + 33554432);
  u16* qb   = (u16*)(ws + 67108864);
  u16* wq_h  = (u16*)(ws + 167772160);
  u16* wkv_h = (u16*)(ws + 176160768);  // [Wk_h; Wv_h] stacked 4096x2048
  u16* wkv_l = (u16*)(ws + 192937984);  // [Wk_l; Wv_l] stacked 4096x2048
  u16* wo_h  = (u16*)(ws + 209715200);
  u64* kpk = (u64*)(ws + 218103808);
  u64* vpk = (u64*)(ws + 220200960);
  u16* att    = x_hi;                   // x_hi dead after projections
  short* pfx8 = (short*)(ws + 134217728); // free region

  split_all<<<4096, 256, 0, stream>>>(x, Wq, Wk, Wv, Wo,
                                      x_hi, x_lo, wq_h,
                                      wkv_h, wkv_l,                     // Wk hi/lo
                                      wkv_h + 4194304, wkv_l + 4194304, // Wv hi/lo
                                      wo_h);

  gemm8p<1,0,8><<<256, 512, 0, stream>>>(x_hi, nullptr, wq_h, nullptr, qb, nullptr,
                                         nullptr, nullptr, 8192, 2048, 2048);
  gemm8p<3,1,16><<<512, 512, 0, stream>>>(x_hi, x_lo, wkv_h, wkv_l, nullptr, nullptr,
                                          kpk, vpk, 8192, 4096, 2048);

  scan_kernel<<<2048, 256, 0, stream>>>(kpk, vpk, pfx8, fstate);
  fused_attn<<<2048, 256, 0, stream>>>(qb, kpk, vpk, pfx8, att);

  gemm8p<1,2,8><<<256, 512, 0, stream>>>(att, nullptr, wo_h, nullptr, nullptr, out,
                                         nullptr, nullptr, 8192, 2048, 2048);
}

// Round 20
// 631.537 us; speedup vs baseline: 1.0280x; 1.0280x over previous
//
#include <hip/hip_runtime.h>
#include <stdint.h>

typedef __attribute__((ext_vector_type(8))) short short8;
typedef __attribute__((ext_vector_type(4))) float f32x4;
typedef unsigned short u16;
typedef unsigned long long u64;

// ---- helpers ----
__device__ __forceinline__ u16 f2bf(float f) {
  uint32_t u = __builtin_bit_cast(uint32_t, f);
  u = (u + 0x7FFFu + ((u >> 16) & 1u)) >> 16;
  return (u16)u;
}
__device__ __forceinline__ float bf2f(u16 h) {
  uint32_t u = ((uint32_t)h) << 16;
  return __builtin_bit_cast(float, u);
}
__device__ __forceinline__ void lds16(const u16* g, u16* l) {
  __builtin_amdgcn_global_load_lds(
      (const __attribute__((address_space(1))) void*)g,
      (__attribute__((address_space(3))) void*)l, 16, 0, 0);
}
// LDS XOR swizzles on u16 indices (16B granule): involutions.
__device__ __forceinline__ int sw256(int i) { return i ^ (((i >> 7) & 7) << 3); }
__device__ __forceinline__ int sw128(int i) { return i ^ (((i >> 6) & 7) << 3); }
// tile-row swizzles: BK=64 rows: flip slot bits[5:3] by row&7
__device__ __forceinline__ int swzA64(int i) { return i ^ (((i >> 6) & 7) << 3); }
// BK=32 rows: flip slot bits[4:3] by (row>>1)&3
__device__ __forceinline__ int swzA32(int i) { return i ^ (((i >> 6) & 3) << 3); }

#define SB0() __builtin_amdgcn_sched_barrier(0)
#define BAR() __builtin_amdgcn_s_barrier()
#define LGKM0() do { asm volatile("s_waitcnt lgkmcnt(0)" ::: "memory"); SB0(); } while (0)
#define VM(n) asm volatile("s_waitcnt vmcnt(" #n ")" ::: "memory")
#define VMNOP do {} while (0)

// ---- fused vectorized split: f32 -> bf16 hi (+ optional lo), all 5 inputs ----
__global__ __launch_bounds__(256) void split_all(
    const float* __restrict__ x,  const float* __restrict__ Wq,
    const float* __restrict__ Wk, const float* __restrict__ Wv,
    const float* __restrict__ Wo,
    u16* __restrict__ xh, u16* __restrict__ xl,
    u16* __restrict__ qh, u16* __restrict__ kh, u16* __restrict__ kl,
    u16* __restrict__ vh, u16* __restrict__ vl, u16* __restrict__ oh)
{
  const int bid = blockIdx.x, t = threadIdx.x;
  if (bid < 2048) {
    for (int i = bid * 256 + t; i < 2097152; i += 2048 * 256) {
      const float4* s = (const float4*)x + 2 * (size_t)i;
      float4 a = s[0], b = s[1];
      float v[8] = {a.x, a.y, a.z, a.w, b.x, b.y, b.z, b.w};
      short8 hi, lo;
#pragma unroll
      for (int j = 0; j < 8; j++) {
        u16 h = f2bf(v[j]);
        hi[j] = (short)h;
        lo[j] = (short)f2bf(v[j] - bf2f(h));
      }
      ((short8*)xh)[i] = hi;
      ((short8*)xl)[i] = lo;
    }
  } else {
    const int seg = (bid - 2048) >> 9;      // 0..3 : Wq, Wk, Wv, Wo
    const int sb  = (bid - 2048) & 511;
    const float* W = seg == 0 ? Wq : seg == 1 ? Wk : seg == 2 ? Wv : Wo;
    u16* H = seg == 0 ? qh : seg == 1 ? kh : seg == 2 ? vh : oh;
    u16* L = seg == 1 ? kl : seg == 2 ? vl : nullptr;
    for (int i = sb * 256 + t; i < 524288; i += 512 * 256) {
      const float4* s = (const float4*)W + 2 * (size_t)i;
      float4 a = s[0], b = s[1];
      float v[8] = {a.x, a.y, a.z, a.w, b.x, b.y, b.z, b.w};
      short8 hi, lo;
#pragma unroll
      for (int j = 0; j < 8; j++) {
        u16 h = f2bf(v[j]);
        hi[j] = (short)h;
        lo[j] = (short)f2bf(v[j] - bf2f(h));
      }
      ((short8*)H)[i] = hi;
      if (L) ((short8*)L)[i] = lo;
    }
  }
}

// ==== 256x256 GEMM body (R18 config, best measured) ====
// 8 waves (2M x 4N), per-wave 128x64 out. Tile T+1 staged in 8KB rounds
// DURING tile T's phases; counted vmcnt keeps stages in flight across raw
// s_barriers (never drains mid-loop). NTN = # of 256-col tiles.
// SPLIT=1: BK=64, 4 quadrant phases. SPLIT=3: BK=32, 3 pass-phases.
// EPI 0: bf16 (b,h,t,d)*qscale | EPI 1: ballot-pack signs -> kpk/vpk | EPI 2: f32
template<int SPLIT, int EPI, int NTN>
__device__ __forceinline__ void gemm_body(
    u16* __restrict__ smem, int bid,
    const u16* __restrict__ Ahi, const u16* __restrict__ Alo,
    const u16* __restrict__ Bhi, const u16* __restrict__ Blo,
    u16* __restrict__ outb, float* __restrict__ outf,
    u64* __restrict__ kpk_p, u64* __restrict__ vpk_p,
    int Mdim, int Ndim, int Kdim)
{
  constexpr int BK   = (SPLIT > 1) ? 32 : 64;
  constexpr int TILE = 256 * BK;                 // u16 per matrix tile
  constexpr int NMAT = (SPLIT > 1) ? 4 : 2;
  constexpr int AOFF_H = 0;
  constexpr int AOFF_L = (SPLIT > 1) ? TILE : 0;
  constexpr int BOFF_H = (SPLIT > 1) ? 2*TILE : TILE;
  constexpr int BOFF_L = (SPLIT > 1) ? 3*TILE : 0;

  const int t = threadIdx.x, l = t & 63;
  const int w = t >> 6;
  const int wm = w >> 2, wn = w & 3;
  const int fr = l & 15, fs = l >> 4;
  // XCD-bijective block swizzle (grid part = 32*NTN, % 8 == 0)
  const int sb = (bid & 7) * (4 * NTN) + (bid >> 3);
  const int m0 = (sb / NTN) * 256, n0 = (sb % NTN) * 256;
  const int NT = Kdim / BK;

  // stage one 8KB round (512 lanes x 16B) of matrix `src` for K-tile kt.
  auto ST = [&](const u16* src, int g0, int moff, int kt, int r) {
    if (kt >= NT) return;
    const int bufb = (kt & 1) * NMAT * TILE;
    int d = r * 4096 + t * 8;
    int row, scol;
    if constexpr (SPLIT == 1) { row = d >> 6; scol = ((d >> 3) & 7) ^ (row & 7); }
    else                      { row = d >> 5; scol = ((d >> 3) & 3) ^ ((row >> 1) & 3); }
    lds16(src + (size_t)(g0 + row) * Kdim + kt * BK + scol * 8,
          smem + bufb + moff + d);
  };

  f32x4 acc[8][4] = {};

#define SWZ(i) ((BK == 64) ? swzA64(i) : swzA32(i))
  // SPLIT=3 readers (one 32-k-slice)
  auto RD8 = [&](short8* dst, int bufb, int off) {
#pragma unroll
    for (int fm = 0; fm < 8; fm++) {
      int ia = (wm*128 + fm*16 + fr)*BK + fs*8;
      dst[fm] = *(const short8*)(smem + bufb + off + SWZ(ia));
    }
  };
  auto RD4 = [&](short8* dst, int bufb, int off) {
#pragma unroll
    for (int fn = 0; fn < 4; fn++) {
      int ib = (wn*64 + fn*16 + fr)*BK + fs*8;
      dst[fn] = *(const short8*)(smem + bufb + off + SWZ(ib));
    }
  };
  // SPLIT=1 readers
  auto RDQ = [&](short8* dst, int bufb, int q) {   // A quadrant q: [i*2+ks]
#pragma unroll
    for (int i = 0; i < 2; i++)
#pragma unroll
      for (int ks = 0; ks < 2; ks++) {
        int ia = (wm*128 + (2*q+i)*16 + fr)*64 + ks*32 + fs*8;
        dst[i*2+ks] = *(const short8*)(smem + bufb + AOFF_H + swzA64(ia));
      }
  };
  auto RDB8 = [&](short8* dst, int bufb) {         // B full: [fn*2+ks]
#pragma unroll
    for (int fn = 0; fn < 4; fn++)
#pragma unroll
      for (int ks = 0; ks < 2; ks++) {
        int ib = (wn*64 + fn*16 + fr)*64 + ks*32 + fs*8;
        dst[fn*2+ks] = *(const short8*)(smem + bufb + BOFF_H + swzA64(ib));
      }
  };

#define PASS32(RA, RB) do {                                                    \
  __builtin_amdgcn_s_setprio(1);                                               \
  _Pragma("unroll") for (int fm_ = 0; fm_ < 8; fm_++)                          \
    _Pragma("unroll") for (int fn_ = 0; fn_ < 4; fn_++)                        \
      acc[fm_][fn_] = __builtin_amdgcn_mfma_f32_16x16x32_bf16(                 \
          (RA)[fm_], (RB)[fn_], acc[fm_][fn_], 0, 0, 0);                       \
  __builtin_amdgcn_s_setprio(0);                                               \
  SB0();                                                                       \
} while (0)

#define PASS16(Q, AQ, BB) do {                                                 \
  __builtin_amdgcn_s_setprio(1);                                               \
  _Pragma("unroll") for (int i_ = 0; i_ < 2; i_++)                             \
    _Pragma("unroll") for (int fn_ = 0; fn_ < 4; fn_++)                        \
      _Pragma("unroll") for (int ks_ = 0; ks_ < 2; ks_++)                      \
        acc[2*(Q)+i_][fn_] = __builtin_amdgcn_mfma_f32_16x16x32_bf16(          \
            (AQ)[i_*2+ks_], (BB)[fn_*2+ks_], acc[2*(Q)+i_][fn_], 0, 0, 0);     \
  __builtin_amdgcn_s_setprio(0);                                               \
  SB0();                                                                       \
} while (0)

// SPLIT=3 tile: 3 phases, stage T+1 rounds Ah,Ah,Bh,Bh | Bl,Bl | Al,Al
#define T3BODY(T, W0, W1, W2) {                                                \
  const int bufb = ((T) & 1) * NMAT * TILE;                                    \
  short8 xah[8], xbh[4], xbl[4], xal[8];                                       \
  RD8(xah, bufb, AOFF_H); RD4(xbh, bufb, BOFF_H);                              \
  ST(Ahi, m0, AOFF_H, (T)+1, 0); ST(Ahi, m0, AOFF_H, (T)+1, 1);                \
  ST(Bhi, n0, BOFF_H, (T)+1, 0); ST(Bhi, n0, BOFF_H, (T)+1, 1);                \
  W0; BAR(); LGKM0(); PASS32(xah, xbh); BAR();                                 \
  RD4(xbl, bufb, BOFF_L);                                                      \
  ST(Blo, n0, BOFF_L, (T)+1, 0); ST(Blo, n0, BOFF_L, (T)+1, 1);                \
  W1; BAR(); LGKM0(); PASS32(xah, xbl); BAR();                                 \
  RD8(xal, bufb, AOFF_L);                                                      \
  ST(Alo, m0, AOFF_L, (T)+1, 0); ST(Alo, m0, AOFF_L, (T)+1, 1);                \
  W2; BAR(); LGKM0(); PASS32(xal, xbh); BAR();                                 \
}

// SPLIT=1 tile: 4 quadrant phases, stage T+1 rounds B0,B1 | B2,B3 | A0,A2 | A1,A3
#define T1BODY(T, W1, W3) {                                                    \
  const int bufb = ((T) & 1) * NMAT * TILE;                                    \
  short8 bb[8], aq[4];                                                         \
  RDB8(bb, bufb); RDQ(aq, bufb, 0);                                            \
  ST(Bhi, n0, BOFF_H, (T)+1, 0); ST(Bhi, n0, BOFF_H, (T)+1, 1);                \
  BAR(); LGKM0(); PASS16(0, aq, bb); BAR();                                    \
  RDQ(aq, bufb, 1);                                                            \
  ST(Bhi, n0, BOFF_H, (T)+1, 2); ST(Bhi, n0, BOFF_H, (T)+1, 3);                \
  W1; BAR(); LGKM0(); PASS16(1, aq, bb); BAR();                                \
  RDQ(aq, bufb, 2);                                                            \
  ST(Ahi, m0, AOFF_H, (T)+1, 0); ST(Ahi, m0, AOFF_H, (T)+1, 2);                \
  BAR(); LGKM0(); PASS16(2, aq, bb); BAR();                                    \
  RDQ(aq, bufb, 3);                                                            \
  ST(Ahi, m0, AOFF_H, (T)+1, 1); ST(Ahi, m0, AOFF_H, (T)+1, 3);                \
  W3; BAR(); LGKM0(); PASS16(3, aq, bb); BAR();                                \
}

  if constexpr (SPLIT > 1) {
    // prologue: T0 fully staged; Ah,Bh landed, Bl,Al (4) left in flight
    ST(Ahi, m0, AOFF_H, 0, 0); ST(Ahi, m0, AOFF_H, 0, 1);
    ST(Bhi, n0, BOFF_H, 0, 0); ST(Bhi, n0, BOFF_H, 0, 1);
    ST(Blo, n0, BOFF_L, 0, 0); ST(Blo, n0, BOFF_L, 0, 1);
    ST(Alo, m0, AOFF_L, 0, 0); ST(Alo, m0, AOFF_L, 0, 1);
    VM(4); BAR();
    for (int T = 0; T < NT - 1; T++) T3BODY(T, VM(6), VM(6), VM(4))
    T3BODY(NT - 1, VM(2), VM(0), VMNOP)
  } else {
    // prologue: T0 staged; Ar1,Ar3 (2) left in flight
    ST(Bhi, n0, BOFF_H, 0, 0); ST(Bhi, n0, BOFF_H, 0, 1);
    ST(Bhi, n0, BOFF_H, 0, 2); ST(Bhi, n0, BOFF_H, 0, 3);
    ST(Ahi, m0, AOFF_H, 0, 0); ST(Ahi, m0, AOFF_H, 0, 2);
    ST(Ahi, m0, AOFF_H, 0, 1); ST(Ahi, m0, AOFF_H, 0, 3);
    VM(2); BAR();
    for (int T = 0; T < NT - 1; T++) T1BODY(T, VM(4), VM(2))
    T1BODY(NT - 1, VM(0), VMNOP)
  }
#undef SWZ
#undef T3BODY
#undef T1BODY
#undef PASS32
#undef PASS16

  if constexpr (EPI == 1) {
    // ballot-pack signs into chunk words. Per (q, fn): 16 ballots; bit
    // (fs*16+fr) of bal[j][r] = sign(row j*16+fs*4+r, col fr). Lane c<16
    // assembles word for col c: bit rc = j*16+fs*4+r.
#pragma unroll
    for (int q = 0; q < 2; q++) {
#pragma unroll
      for (int fn = 0; fn < 4; fn++) {
        u64 bal[4][4];
#pragma unroll
        for (int j = 0; j < 4; j++)
#pragma unroll
          for (int r = 0; r < 4; r++)
            bal[j][r] = __ballot(acc[4*q + j][fn][r] < 0.f);
        if (l < 16) {
          u64 wq = 0;
#pragma unroll
          for (int j = 0; j < 4; j++)
#pragma unroll
            for (int r = 0; r < 4; r++) {
              u64 x = (bal[j][r] >> l) & 0x0001000100010001ULL;
              u64 y = (x & 1) | ((x >> 12) & 0x10) |
                      ((x >> 24) & 0x100) | ((x >> 36) & 0x1000);
              wq |= y << (j*16 + r);
            }
          int gmc = m0 + wm*128 + q*64;
          int gn  = n0 + wn*64 + fn*16 + l;
          int b = gmc >> 12, n = (gmc & 4095) >> 6;
          int kv = gn >> 11, h = (gn >> 7) & 15, dd = gn & 127;
          u64* dst = kv ? vpk_p : kpk_p;
          dst[((size_t)((b*16 + h)*64 + n))*128 + dd] = wq;
        }
      }
    }
  } else {
    const float qscale = 0.08838834764831843f; // 1/sqrt(128)
#pragma unroll
    for (int fm = 0; fm < 8; fm++)
#pragma unroll
      for (int fn = 0; fn < 4; fn++)
#pragma unroll
        for (int r = 0; r < 4; r++) {
          int gm = m0 + wm*128 + fm*16 + fs*4 + r;
          int gn = n0 + wn*64 + fn*16 + fr;
          float val = acc[fm][fn][r];
          if constexpr (EPI == 2) {
            outf[(size_t)gm * Ndim + gn] = val;
          } else {
            int b = gm >> 12, tt = gm & 4095, h = gn >> 7, dd = gn & 127;
            size_t idx = (((size_t)(b*16 + h))*4096 + tt)*128 + dd;
            outb[idx] = f2bf(val * qscale);
          }
        }
  }
}

// O projection: standalone (depends on att)
__global__ __launch_bounds__(512, 2) void gemm_o(
    const u16* __restrict__ A, const u16* __restrict__ B,
    float* __restrict__ outf)
{
  __shared__ __align__(16) u16 smem[65536];   // 128 KiB
  gemm_body<1, 2, 8>(smem, blockIdx.x, A, nullptr, B, nullptr,
                     nullptr, outf, nullptr, nullptr, 8192, 2048, 2048);
}

// MERGED independent Q + KV projections: blocks 0-511 KV, 512-767 Q.
// Removes the inter-dispatch drain/launch gap; Q blocks back-fill the KV tail.
__global__ __launch_bounds__(512, 2) void gemm_qkv(
    const u16* __restrict__ xh, const u16* __restrict__ xl,
    const u16* __restrict__ wq, const u16* __restrict__ wkvh,
    const u16* __restrict__ wkvl,
    u16* __restrict__ qb, u64* __restrict__ kpk, u64* __restrict__ vpk)
{
  __shared__ __align__(16) u16 smem[65536];   // 128 KiB
  if (blockIdx.x < 512)
    gemm_body<3, 1, 16>(smem, blockIdx.x, xh, xl, wkvh, wkvl,
                        nullptr, nullptr, kpk, vpk, 8192, 4096, 2048);
  else
    gemm_body<1, 0, 8>(smem, blockIdx.x - 512, xh, nullptr, wq, nullptr,
                       qb, nullptr, nullptr, nullptr, 8192, 2048, 2048);
}

// ---- parallel exact prefix-state: stride-8 int16 checkpoints + final state
//      (writes fstate [bh][d][e] directly via LDS e-pair exchange) ----
__global__ __launch_bounds__(256) void scan_kernel(
    const u64* __restrict__ kp, const u64* __restrict__ vp,
    short* __restrict__ pfx8, float* __restrict__ fstate)
{
  __shared__ float xch[256];
  const int t = threadIdx.x;
  const int bh = blockIdx.x >> 6, ep = blockIdx.x & 63;
  const int e = ep * 2 + (t >> 7), d = t & 127;
  const size_t base = (size_t)bh * 64 * 128;
  int s = 0;
  for (int n = 0; n < 64; n++) {
    if ((n & 7) == 0)
      pfx8[((size_t)(bh*8 + (n>>3))*128 + e)*128 + d] = (short)s;
    u64 kw = kp[base + (size_t)n*128 + d];
    u64 vw = vp[base + (size_t)n*128 + e];
    s += 64 - 2*__popcll(kw ^ vw);
  }
  xch[t] = (float)s;
  __syncthreads();
  if (t < 128) {
    float2 p;
    p.x = xch[t];          // (e = 2*ep,   d = t)
    p.y = xch[t + 128];    // (e = 2*ep+1, d = t)
    *(float2*)&fstate[((size_t)bh*128 + t)*128 + ep*2] = p;
  }
}

// ---- fused intra + cross per (b,h,chunk): fully parallel over 2048 blocks ----
// Q held in REGISTERS (4 short8/lane, wave-local rows, reused 3x). LDS 32KB.
__global__ __launch_bounds__(256) void fused_attn(
    const u16* __restrict__ q,
    const u64* __restrict__ kp, const u64* __restrict__ vp,
    const short* __restrict__ pfx8, u16* __restrict__ att)
{
  __shared__ __align__(16) u16 smem[16384];  // 32KB
  u16* sP1 = smem;          // K [64][128] sw256 -> PThi [64][128] sw256
  u16* sP2 = smem + 8192;   // V^T [128][64] sw128 -> PTlo [64][128] sw256
  u16* sS  = sP1 + 4096;    // [64][64] sw128, OVERLAYS sP1 rows 32-63

  const int t = threadIdx.x, l = t & 63, w = t >> 6;
  const int blk = blockIdx.x, bh = blk >> 6, n = blk & 63;
  const int b = bh >> 4, hh = bh & 15;
  const int fr = l & 15, fs = l >> 4;
  const size_t qbase = (((size_t)bh * 4096) + n * 64) * 128;
  const size_t pbase = (size_t)bh * 64 * 128;

  // Q fragments direct global->reg (issued first; latency hides under unpack)
  short8 qv[4];
#pragma unroll
  for (int kk = 0; kk < 4; kk++)
    qv[kk] = *(const short8*)(q + qbase + (size_t)(w*16 + fr)*128 + kk*32 + fs*8);

  // unpack K (row-major [c][d], sw256) and V^T ([d][c], sw128) from bit words
  {
    const u64* krow = kp + pbase + (size_t)n*128;
    int d = (t & 63) * 2, c0 = (t >> 6) * 16;
    u64 w0 = krow[d], w1 = krow[d+1];
#pragma unroll
    for (int i = 0; i < 16; i++) {
      int c = c0 + i;
      uint32_t b0 = ((w0 >> c) & 1ull) ? 0xBF80u : 0x3F80u;
      uint32_t b1 = ((w1 >> c) & 1ull) ? 0xBF80u : 0x3F80u;
      *(uint32_t*)(sP1 + sw256(c*128 + d)) = b0 | (b1 << 16);
    }
  }
  {
    int d = t >> 1, ch = (t & 1) * 32;
    u64 wv = vp[pbase + (size_t)n*128 + d];
#pragma unroll
    for (int c = 0; c < 32; c += 2) {
      uint32_t b0 = ((wv >> (ch + c)) & 1ull)     ? 0xBF80u : 0x3F80u;
      uint32_t b1 = ((wv >> (ch + c + 1)) & 1ull) ? 0xBF80u : 0x3F80u;
      int li = d*64 + ch + c;
      *(uint32_t*)(sP2 + sw128(li)) = b0 | (b1 << 16);
    }
  }
  __syncthreads();

  // phase B: scores = Q K^T, causal mask
  f32x4 accS[4] = {};
#pragma unroll
  for (int kk = 0; kk < 4; kk++) {
#pragma unroll
    for (int fn = 0; fn < 4; fn++) {
      int lb = (fn*16 + fr)*128 + kk*32 + fs*8;
      short8 bb = *(const short8*)(sP1 + sw256(lb));
      accS[fn] = __builtin_amdgcn_mfma_f32_16x16x32_bf16(qv[kk], bb, accS[fn], 0, 0, 0);
    }
  }
  __syncthreads();   // all waves done reading sP1(K) before sS overlay write
#pragma unroll
  for (int fn = 0; fn < 4; fn++)
#pragma unroll
    for (int r = 0; r < 4; r++) {
      int i = w*16 + fs*4 + r, j = fn*16 + fr;
      float v = (j <= i) ? accS[fn][r] : 0.f;
      sS[sw128(i*64 + j)] = f2bf(v);
    }
  __syncthreads();

  // phase C: intra = sS @ V
  f32x4 accI[8] = {};
#pragma unroll
  for (int kk = 0; kk < 2; kk++) {
    int la = (w*16 + fr)*64 + kk*32 + fs*8;
    short8 a = *(const short8*)(sS + sw128(la));
#pragma unroll
    for (int fn = 0; fn < 8; fn++) {
      int lb = (fn*16 + fr)*64 + kk*32 + fs*8;
      short8 bb = *(const short8*)(sP2 + sw128(lb));
      accI[fn] = __builtin_amdgcn_mfma_f32_16x16x32_bf16(a, bb, accI[fn], 0, 0, 0);
    }
  }
  __syncthreads();

  // cross term, two e-halves; prefix rebuilt exactly per half
  const int m0 = n & ~7, cnt = n & 7;
  for (int hf = 0; hf < 2; hf++) {
#pragma unroll
    for (int p = 0; p < 4; p++) {
      int erow = p*16 + (t>>4);
      int e = hf*64 + erow;
      const short* ps = pfx8 + ((size_t)(bh*8 + (n>>3))*128 + e)*128 + (t&15)*8;
      short8 pv = *(const short8*)ps;
      int accj[8];
#pragma unroll
      for (int j = 0; j < 8; j++) accj[j] = pv[j];
      for (int m = 0; m < cnt; m++) {
        u64 vw = vp[pbase + (size_t)(m0+m)*128 + e];
#pragma unroll
        for (int j = 0; j < 8; j++) {
          u64 kw = kp[pbase + (size_t)(m0+m)*128 + (t&15)*8 + j];
          accj[j] += 64 - 2*__popcll(kw ^ vw);
        }
      }
      short8 hi, lo;
#pragma unroll
      for (int j = 0; j < 8; j++) {
        hi[j] = (short)f2bf((float)(accj[j] >> 5));
        lo[j] = (short)f2bf((float)(accj[j] & 31));
      }
      int pi = sw256(erow*128 + (t&15)*8);
      *(short8*)(sP1 + pi) = hi;
      *(short8*)(sP2 + pi) = lo;
    }
    __syncthreads();

    f32x4 acch[4] = {}, accl[4] = {};
#pragma unroll
    for (int kk = 0; kk < 4; kk++) {
#pragma unroll
      for (int fn = 0; fn < 4; fn++) {
        int pb = sw256((fn*16 + fr)*128 + kk*32 + fs*8);
        acch[fn] = __builtin_amdgcn_mfma_f32_16x16x32_bf16(qv[kk], *(const short8*)(sP1 + pb), acch[fn], 0, 0, 0);
        accl[fn] = __builtin_amdgcn_mfma_f32_16x16x32_bf16(qv[kk], *(const short8*)(sP2 + pb), accl[fn], 0, 0, 0);
      }
    }
#pragma unroll
    for (int fn = 0; fn < 4; fn++)
#pragma unroll
      for (int r = 0; r < 4; r++) {
        int c = w*16 + fs*4 + r;
        int dcol = hf*64 + fn*16 + fr;
        float val = accI[hf*4+fn][r] + 32.f*acch[fn][r] + accl[fn][r];
        size_t idx = ((size_t)(b*4096 + n*64 + c))*2048 + hh*128 + dcol;
        att[idx] = f2bf(val);
      }
    __syncthreads();  // before next half overwrites sP1/sP2
  }
}

extern "C" void kernel_launch(void* const* d_in, const int* in_sizes, int n_in,
                              void* d_out, int out_size, void* d_ws, size_t ws_size,
                              hipStream_t stream) {
  (void)in_sizes; (void)n_in; (void)out_size; (void)ws_size;
  const float* x  = (const float*)d_in[0];
  const float* Wq = (const float*)d_in[1];
  const float* Wk = (const float*)d_in[2];
  const float* Wv = (const float*)d_in[3];
  const float* Wo = (const float*)d_in[4];
  float* out = (float*)d_out;
  float* fstate = out + (size_t)16777216; // B*T*D

  char* ws = (char*)d_ws;
  u16* x_hi = (u16*)(ws + 0);           // later aliased as att
  u16* x_lo = (u16*)(ws + 33554432);
  u16* qb   = (u16*)(ws + 67108864);
  u16* wq_h  = (u16*)(ws + 167772160);
  u16* wkv_h = (u16*)(ws + 176160768);  // [Wk_h; Wv_h] stacked 4096x2048
  u16* wkv_l = (u16*)(ws + 192937984);  // [Wk_l; Wv_l] stacked 4096x2048
  u16* wo_h  = (u16*)(ws + 209715200);
  u64* kpk = (u64*)(ws + 218103808);
  u64* vpk = (u64*)(ws + 220200960);
  u16* att    = x_hi;                   // x_hi dead after projections
  short* pfx8 = (short*)(ws + 134217728); // free region

  split_all<<<4096, 256, 0, stream>>>(x, Wq, Wk, Wv, Wo,
                                      x_hi, x_lo, wq_h,
                                      wkv_h, wkv_l,                     // Wk hi/lo
                                      wkv_h + 4194304, wkv_l + 4194304, // Wv hi/lo
                                      wo_h);

  gemm_qkv<<<768, 512, 0, stream>>>(x_hi, x_lo, wq_h, wkv_h, wkv_l,
                                    qb, kpk, vpk);

  scan_kernel<<<2048, 256, 0, stream>>>(kpk, vpk, pfx8, fstate);
  fused_attn<<<2048, 256, 0, stream>>>(qb, kpk, vpk, pfx8, att);

  gemm_o<<<256, 512, 0, stream>>>(att, wo_h, out);
}